// Round 3
// baseline (355.631 us; speedup 1.0000x reference)
//
#include <hip/hip_runtime.h>

// PWC-Net 9x9 correlation — r3: conflict-free PX=4 layout, S-only LDS.
//
// r2 post-mortem: 153us/dispatch, SQ_LDS_BANK_CONFLICT=9.29M. The PX=8
// layout read 16B at 32B lane stride -> only half the LDS banks used,
// 16-way aliasing. This version maps 48 lanes x 4 pixels per row so every
// ds_read_b128 is lane-contiguous (8 words/bank/wave = zero conflicts).
// F drops out of LDS entirely: with the contiguous mapping each lane's F
// pixels are private, so F is a coalesced global float4 load, register
// double-buffered (prefetch c+1 during compute c). Only S (cross-lane
// window reuse) stays in LDS, double-buffered via global_load_lds.
//
// OOB handling unchanged in spirit:
//  - second rows outside [0,H): per-lane staging source -> zeroed
//    __device__ row, stride 0.
//  - x window halo: thread-constant LDS pointer -> 16B zero pad.
//
// Numerics: same channel-sequential fmaf chain, same 1/C scale.

namespace {
constexpr int kC = 128;
constexpr int kH = 112;
constexpr int kW = 192;
constexpr int kD = 4;            // max displacement
constexpr int kKD = 9;           // 2*kD+1
constexpr int kHW = kH * kW;     // 21504
constexpr long long kCHW = (long long)kC * kHW;

constexpr int PX = 4;            // pixels per thread along x
constexpr int XG = kW / PX;      // 48 x-groups (one row = 48 lanes, 16B each)
constexpr int YT = 8;            // rows per block
constexpr int NT = XG * YT;      // 384 threads = 6 waves
constexpr int TILE = YT * kW;    // 1536 floats per staged S tile
}  // namespace

// 768B of zeros: staging source for out-of-image second rows.
__device__ __attribute__((aligned(16))) float g_zero_row[kW] = {};

typedef const __attribute__((address_space(1))) void* gas_ptr;
typedef __attribute__((address_space(3))) void* las_ptr;

__device__ __forceinline__ void gload16(const float* g, float* l) {
  __builtin_amdgcn_global_load_lds((gas_ptr)g, (las_ptr)l, 16, 0, 0);
}

__global__ __launch_bounds__(NT, 6)
void corr81_kernel(const float* __restrict__ first,
                   const float* __restrict__ second,
                   float* __restrict__ out) {
  __shared__ __align__(16) float zpad[4];      // x-halo zeros
  __shared__ __align__(16) float Sb[2][TILE];  // second tiles (double buffer)

  const int g = blockIdx.x;
  const int b = g & 7;             // batch -> XCD slab
  const int i = g >> 3;
  const int dy = i % kKD;          // dy innermost -> L2 sliding window
  const int y0 = (i / kKD) * YT;

  const int tid = threadIdx.x;
  const int xg = tid % XG;         // lane's x-group (contiguous 16B per lane)
  const int yl = tid / XG;         // lane's row in tile
  const int px0 = xg * PX;
  const int ys0 = y0 + dy - kD;    // first staged second-row (may be OOB)

  if (tid == 0) { zpad[0] = 0.f; zpad[1] = 0.f; zpad[2] = 0.f; zpad[3] = 0.f; }

  // ---- S staging source (per lane, one 16B per channel): tile float
  // offset tid*4 = row tid/48, col (tid%48)*4. Rows OOB -> zero row.
  const float* ssrc;
  long long sstr;
  {
    const int r = tid / XG;
    const int col = (tid % XG) * PX;
    const int ysr = ys0 + r;
    const bool inb = (unsigned)ysr < (unsigned)kH;
    ssrc = inb ? (second + (long long)b * kCHW + (long long)ysr * kW + col)
               : (g_zero_row + col);
    sstr = inb ? (long long)kHW : 0ll;
  }

  // ---- F source: lane's own 4 pixels, coalesced float4, register dbuf.
  const float* fp = first + (long long)b * kCHW + (long long)(y0 + yl) * kW + px0;

  float acc[PX][kKD];
#pragma unroll
  for (int p = 0; p < PX; ++p)
#pragma unroll
    for (int d = 0; d < kKD; ++d) acc[p][d] = 0.0f;

  // thread-constant compute pointers per buffer
  const float* s1p[2] = {&Sb[0][yl * kW + px0], &Sb[1][yl * kW + px0]};
  const float* w0p[2] = {(xg == 0) ? zpad : s1p[0] - PX,
                         (xg == 0) ? zpad : s1p[1] - PX};
  const float* w2p[2] = {(xg == XG - 1) ? zpad : s1p[0] + PX,
                         (xg == XG - 1) ? zpad : s1p[1] + PX};

  auto stage = [&](int P) {        // one gload16 per lane = 6KB tile
    gload16(ssrc, &Sb[P][tid * PX]);
    ssrc += sstr;
  };

  auto compute = [&](int P, const float4& f) {
    const float4 w0 = *(const float4*)(w0p[P]);   // floats [px0-4, px0)
    const float4 w1 = *(const float4*)(s1p[P]);   // floats [px0, px0+4)
    const float4 w2 = *(const float4*)(w2p[P]);   // floats [px0+4, px0+8)
    const float fa[PX] = {f.x, f.y, f.z, f.w};
    const float sw[12] = {w0.x, w0.y, w0.z, w0.w, w1.x, w1.y, w1.z, w1.w,
                          w2.x, w2.y, w2.z, w2.w};
#pragma unroll
    for (int p = 0; p < PX; ++p)
#pragma unroll
      for (int d = 0; d < kKD; ++d)
        acc[p][d] = fmaf(fa[p], sw[p + d], acc[p][d]);
  };

  // ---- software-pipelined channel loop (unroll 2) ----
  float4 fcur, fnext;
  stage(0);                          // S for c=0
  fcur = *(const float4*)fp; fp += kHW;
  __syncthreads();                   // buf0 + zpad ready
  for (int c = 0; c < kC; c += 2) {
    stage(1);                        // S for c+1
    fnext = *(const float4*)fp; fp += kHW;   // F for c+1
    compute(0, fcur);                // channel c
    __syncthreads();                 // buf1 ready; buf0 consumed
    if (c + 2 < kC) {
      stage(0);                      // S for c+2
      fcur = *(const float4*)fp; fp += kHW;  // F for c+2
    }
    compute(1, fnext);               // channel c+1
    __syncthreads();                 // buf0 ready; buf1 consumed
  }

  // epilogue: 9 dx channels x 4 px, coalesced dwordx4 stores
  const float scale = 1.0f / (float)kC;
  float* obase = out + ((long long)b * 81 + (long long)dy * kKD) * kHW +
                 (long long)(y0 + yl) * kW + px0;
#pragma unroll
  for (int d = 0; d < kKD; ++d) {
    float4 o = make_float4(acc[0][d] * scale, acc[1][d] * scale,
                           acc[2][d] * scale, acc[3][d] * scale);
    *(float4*)(obase + (long long)d * kHW) = o;
  }
}

extern "C" void kernel_launch(void* const* d_in, const int* in_sizes, int n_in,
                              void* d_out, int out_size, void* d_ws, size_t ws_size,
                              hipStream_t stream) {
  const float* first = (const float*)d_in[0];
  const float* second = (const float*)d_in[1];
  float* out = (float*)d_out;

  const int grid = 8 * (kH / YT) * kKD;  // 8 * 14 * 9 = 1008 blocks
  corr81_kernel<<<grid, NT, 0, stream>>>(first, second, out);
}